// Round 1
// baseline (129.809 us; speedup 1.0000x reference)
//
#include <hip/hip_runtime.h>
#include <math.h>

#define NN 8192

typedef __attribute__((ext_vector_type(8))) short short8;
typedef __attribute__((ext_vector_type(4))) short short4v;
typedef __attribute__((ext_vector_type(4))) float f32x4;
typedef __attribute__((ext_vector_type(4))) int int4v;

__device__ __forceinline__ short f2bf(float f) {
    union { float f; unsigned u; } v; v.f = f;
    unsigned r = v.u + 0x7fffu + ((v.u >> 16) & 1u);
    return (short)(r >> 16);
}

__device__ __forceinline__ f32x4 zero4() {
    f32x4 v; v[0] = 0.f; v[1] = 0.f; v[2] = 0.f; v[3] = 0.f; return v;
}

// ---------- K0: WT[f][k] = bf16(W[k][f]) ----------
__global__ void k0_wt(const float* __restrict__ W, short* __restrict__ WT) {
    int idx = blockIdx.x * 256 + threadIdx.x;
    if (idx < 256 * 128) {
        int k = idx & 255;
        int f = idx >> 8;
        WT[f * 256 + k] = f2bf(W[k * 128 + f]);
    }
}

// ---------- K1: h = x@W (bf16 MFMA, fp32 acc); s1=h@a1, s2=h@a2 (fp32); hT = h^T bf16 ----------
__global__ __launch_bounds__(128) void k1_h(
        const float* __restrict__ x, const short* __restrict__ WT,
        const float* __restrict__ a, short* __restrict__ hT,
        float* __restrict__ s1, float* __restrict__ s2) {
    const int w = threadIdx.x >> 6;
    const int l = threadIdx.x & 63;
    const int quad = l >> 4;
    const int fr = l & 15;
    const int i0 = blockIdx.x * 32 + w * 16;

    f32x4 acc[8];
#pragma unroll
    for (int t = 0; t < 8; ++t) acc[t] = zero4();

    const float* xrow = x + (size_t)(i0 + fr) * 256;
#pragma unroll
    for (int kk = 0; kk < 8; ++kk) {
        const int k0 = kk * 32 + quad * 8;
        f32x4 xa = *(const f32x4*)(xrow + k0);
        f32x4 xb = *(const f32x4*)(xrow + k0 + 4);
        short8 av;
#pragma unroll
        for (int e = 0; e < 4; ++e) { av[e] = f2bf(xa[e]); av[4 + e] = f2bf(xb[e]); }
#pragma unroll
        for (int t = 0; t < 8; ++t) {
            short8 bv = *(const short8*)(WT + (t * 16 + fr) * 256 + k0);
            acc[t] = __builtin_amdgcn_mfma_f32_16x16x32_bf16(av, bv, acc[t], 0, 0, 0);
        }
    }

    // s1/s2 from fp32 accumulators: s[i] = sum_f h[i][f]*a[f]
    float s1p[4] = {0.f, 0.f, 0.f, 0.f};
    float s2p[4] = {0.f, 0.f, 0.f, 0.f};
#pragma unroll
    for (int t = 0; t < 8; ++t) {
        float a1v = a[t * 16 + fr];
        float a2v = a[128 + t * 16 + fr];
#pragma unroll
        for (int r = 0; r < 4; ++r) {
            s1p[r] += acc[t][r] * a1v;
            s2p[r] += acc[t][r] * a2v;
        }
    }
#pragma unroll
    for (int r = 0; r < 4; ++r) {
#pragma unroll
        for (int m = 1; m < 16; m <<= 1) {
            s1p[r] += __shfl_xor(s1p[r], m, 64);
            s2p[r] += __shfl_xor(s2p[r], m, 64);
        }
    }
    if (fr == 0) {
#pragma unroll
        for (int r = 0; r < 4; ++r) {
            s1[i0 + quad * 4 + r] = s1p[r];
            s2[i0 + quad * 4 + r] = s2p[r];
        }
    }

    // hT[f][i] bf16 (so K2 B-fragments are 16B-contiguous along j)
#pragma unroll
    for (int t = 0; t < 8; ++t) {
        short4v hv;
#pragma unroll
        for (int r = 0; r < 4; ++r) hv[r] = f2bf(acc[t][r]);
        *(short4v*)(hT + (size_t)(t * 16 + fr) * NN + i0 + quad * 4) = hv;
    }
}

// ---------- K2: fused masked softmax + PV (bf16 MFMA) + ELU ----------
__global__ __launch_bounds__(512, 2) void k2_attn(
        const int* __restrict__ adj, const short* __restrict__ hT,
        const float* __restrict__ s1g, const float* __restrict__ s2g,
        float* __restrict__ out) {
    __shared__ float red[8192];   // 2 reduction regions of 16KB
    __shared__ float zbuf[256];   // per-wave row-sum partials

    const int w = threadIdx.x >> 6;
    const int l = threadIdx.x & 63;
    const int quad = l >> 4;
    const int fr = l & 15;
    const int i0 = blockIdx.x * 32;

    const float s1v0 = s1g[i0 + fr];
    const float s1v1 = s1g[i0 + 16 + fr];

    f32x4 acc[2][8];
#pragma unroll
    for (int m = 0; m < 2; ++m)
#pragma unroll
        for (int t = 0; t < 8; ++t) acc[m][t] = zero4();
    float zacc0 = 0.f, zacc1 = 0.f;

    const size_t row0 = (size_t)(i0 + fr) * NN;
    const size_t row1 = (size_t)(i0 + 16 + fr) * NN;

    // prologue: prefetch first adj tile for this wave
    int4v g00, g01, g10, g11;
    {
        const int j = w * 32 + quad * 8;
        g00 = *(const int4v*)(adj + row0 + j);
        g01 = *(const int4v*)(adj + row0 + j + 4);
        g10 = *(const int4v*)(adj + row1 + j);
        g11 = *(const int4v*)(adj + row1 + j + 4);
    }

    for (int sj = w; sj < 256; sj += 8) {
        const int j = sj * 32 + quad * 8;
        // B fragments + s2 FIRST, adj prefetch AFTER -> waiting on s2/bv leaves
        // the next-step adj loads outstanding across the MFMAs (vmcnt FIFO).
        short8 bv[8];
#pragma unroll
        for (int t = 0; t < 8; ++t)
            bv[t] = *(const short8*)(hT + (size_t)(t * 16 + fr) * NN + j);
        f32x4 s2a = *(const f32x4*)(s2g + j);
        f32x4 s2b = *(const f32x4*)(s2g + j + 4);

        const int sjn = (sj + 8 < 256) ? (sj + 8) : sj;
        const int jn = sjn * 32 + quad * 8;
        int4v n00 = *(const int4v*)(adj + row0 + jn);
        int4v n01 = *(const int4v*)(adj + row0 + jn + 4);
        int4v n10 = *(const int4v*)(adj + row1 + jn);
        int4v n11 = *(const int4v*)(adj + row1 + jn + 4);

        short8 pa0, pa1;
        float zs0 = 0.f, zs1 = 0.f;
#pragma unroll
        for (int e = 0; e < 8; ++e) {
            const float s2e = (e < 4) ? s2a[e & 3] : s2b[e & 3];
            const int gv0 = (e < 4) ? g00[e & 3] : g01[e & 3];
            const int gv1 = (e < 4) ? g10[e & 3] : g11[e & 3];
            float sA = s1v0 + s2e;
            float sB = s1v1 + s2e;
            float tA = fmaxf(sA, 0.2f * sA) * 1.44269504088896f;
            float tB = fmaxf(sB, 0.2f * sB) * 1.44269504088896f;
            float p0 = (gv0 > 0) ? exp2f(tA) : 0.f;
            float p1 = (gv1 > 0) ? exp2f(tB) : 0.f;
            zs0 += p0; zs1 += p1;
            pa0[e] = f2bf(p0);
            pa1[e] = f2bf(p1);
        }
        zacc0 += zs0; zacc1 += zs1;

#pragma unroll
        for (int t = 0; t < 8; ++t) {
            acc[0][t] = __builtin_amdgcn_mfma_f32_16x16x32_bf16(pa0, bv[t], acc[0][t], 0, 0, 0);
            acc[1][t] = __builtin_amdgcn_mfma_f32_16x16x32_bf16(pa1, bv[t], acc[1][t], 0, 0, 0);
        }
        g00 = n00; g01 = n01; g10 = n10; g11 = n11;
    }

    // Z partials: reduce over quads (same fr -> same row)
    zacc0 += __shfl_xor(zacc0, 16, 64);
    zacc0 += __shfl_xor(zacc0, 32, 64);
    zacc1 += __shfl_xor(zacc1, 16, 64);
    zacc1 += __shfl_xor(zacc1, 32, 64);
    if (l < 16) {
        zbuf[w * 32 + l] = zacc0;
        zbuf[w * 32 + 16 + l] = zacc1;
    }

    auto rwrite = [&](int r) {
        float* base = red + r * 4096;
#pragma unroll
        for (int m = 0; m < 2; ++m)
#pragma unroll
            for (int t = 0; t < 8; ++t)
                *(f32x4*)(base + ((m * 8 + t) * 64 + l) * 4) = acc[m][t];
    };
    auto radd = [&](int r) {
        const float* base = red + r * 4096;
#pragma unroll
        for (int m = 0; m < 2; ++m)
#pragma unroll
            for (int t = 0; t < 8; ++t)
                acc[m][t] += *(const f32x4*)(base + ((m * 8 + t) * 64 + l) * 4);
    };

    // 8-way tree reduction into wave 0 with 2 regions
    if (w == 4) rwrite(0);
    if (w == 5) rwrite(1);
    __syncthreads();
    if (w == 0) radd(0);          // w0 = w0+w4
    if (w == 1) radd(1);          // w1 = w1+w5
    __syncthreads();
    if (w == 6) rwrite(0);
    if (w == 7) rwrite(1);
    __syncthreads();
    if (w == 2) { radd(0); rwrite(0); }   // R0 = w2+w6
    if (w == 3) { radd(1); rwrite(1); }   // R1 = w3+w7
    __syncthreads();
    if (w == 0) radd(0);                  // w0 = w0+w4+w2+w6
    if (w == 1) { radd(1); rwrite(1); }   // R1 = w1+w5+w3+w7
    __syncthreads();

    if (w == 0) {
        radd(1);  // w0 = sum of all 8 waves
#pragma unroll
        for (int m = 0; m < 2; ++m) {
#pragma unroll
            for (int r = 0; r < 4; ++r) {
                const int irow = m * 16 + quad * 4 + r;
                float z = 0.f;
#pragma unroll
                for (int ww = 0; ww < 8; ++ww) z += zbuf[ww * 32 + irow];
                const float inv = 1.0f / z;
                float* orow = out + (size_t)(i0 + irow) * 128;
#pragma unroll
                for (int t = 0; t < 8; ++t) {
                    float v = acc[m][t][r] * inv;
                    orow[t * 16 + fr] = (v > 0.f) ? v : expm1f(v);
                }
            }
        }
    }
}

extern "C" void kernel_launch(void* const* d_in, const int* in_sizes, int n_in,
                              void* d_out, int out_size, void* d_ws, size_t ws_size,
                              hipStream_t stream) {
    const float* x   = (const float*)d_in[0];   // 8192 x 256
    const float* W   = (const float*)d_in[1];   // 256 x 128
    const float* a   = (const float*)d_in[2];   // 256
    const int*   adj = (const int*)d_in[3];     // 8192 x 8192
    float* out = (float*)d_out;                 // 8192 x 128

    char* ws = (char*)d_ws;
    short* hT = (short*)ws;                                 // 128 x 8192 bf16 = 2 MB
    float* s1 = (float*)(ws + (size_t)2 * 1024 * 1024);     // 32 KB
    float* s2 = (float*)(ws + (size_t)2 * 1024 * 1024 + 32768);
    short* WT = (short*)(ws + (size_t)2 * 1024 * 1024 + 65536); // 128 x 256 bf16

    k0_wt<<<128, 256, 0, stream>>>(W, WT);
    k1_h<<<256, 128, 0, stream>>>(x, WT, a, hT, s1, s2);
    k2_attn<<<256, 512, 0, stream>>>(adj, hT, s1, s2, out);
}